// Round 1
// baseline (2523.015 us; speedup 1.0000x reference)
//
#include <hip/hip_runtime.h>

// Problem constants (LLaMA_5669356831047)
#define BB   2
#define TT   1024
#define HH   16
#define DD   1024
#define HDD  64
#define FFD  4096
#define VV   32000
#define LLAY 2
// NOTE: reference rope diag is identically 1.0 (theta = (10000**-2k)//HD == 0) -> RoPE is identity.
// Dtype contract: ALL float tensors fp32; output fp32. bf16 internally for MFMA.

typedef __bf16 bf16x8 __attribute__((ext_vector_type(8)));
typedef float  f32x4  __attribute__((ext_vector_type(4)));

__device__ __forceinline__ float bf2f(ushort u) {
    return __uint_as_float(((unsigned int)u) << 16);
}
__device__ __forceinline__ ushort f2bf(float f) {
    unsigned int u = __float_as_uint(f);
    u += 0x7fffu + ((u >> 16) & 1u);   // round-to-nearest-even
    return (ushort)(u >> 16);
}

// async global->LDS, 16B per lane. LDS dest must be wave-uniform base; HW
// writes base + lane*16 (learn_hip m97/m104).
__device__ __forceinline__ void gl_lds16(const ushort* g, ushort* l) {
    typedef const __attribute__((address_space(1))) unsigned int* gp_t;
    typedef __attribute__((address_space(3))) unsigned int* lp_t;
    __builtin_amdgcn_global_load_lds((gp_t)g, (lp_t)l, 16, 0, 0);
}

// ---------------------------------------------------------------------------
// Embedding gather: x[row][:] = emb[idx[row]][:]   (fp32 -> fp32)
__global__ void embed_k(const int* __restrict__ idx, const float* __restrict__ emb,
                        float* __restrict__ x) {
    int row = blockIdx.x, tid = threadIdx.x;
    int e = idx[row];
    float4 f = *(const float4*)(emb + (size_t)e * DD + tid * 4);
    *(float4*)(x + (size_t)row * DD + tid * 4) = f;
}

// ---------------------------------------------------------------------------
// RMSNorm: h = x * rsqrt(mean(x^2)+eps) * w   (fp32 in, bf16 out). 1 block/row.
__global__ __launch_bounds__(256) void rmsnorm_k(const float* __restrict__ x,
                                                 const float* __restrict__ w,
                                                 ushort* __restrict__ h) {
    int row = blockIdx.x, tid = threadIdx.x;
    int wave = tid >> 6, lane = tid & 63;
    const float* xr = x + (size_t)row * DD;
    float4 xv = *(const float4*)(xr + tid * 4);
    float s = xv.x * xv.x + xv.y * xv.y + xv.z * xv.z + xv.w * xv.w;
    for (int off = 32; off; off >>= 1) s += __shfl_xor(s, off, 64);
    __shared__ float red[4];
    if (lane == 0) red[wave] = s;
    __syncthreads();
    float tot = red[0] + red[1] + red[2] + red[3];
    float rs = rsqrtf(tot * (1.0f / DD) + 1.1920929e-07f);
    float4 wv = *(const float4*)(w + tid * 4);
    ushort4 hv;
    hv.x = f2bf(xv.x * rs * wv.x);
    hv.y = f2bf(xv.y * rs * wv.y);
    hv.z = f2bf(xv.z * rs * wv.z);
    hv.w = f2bf(xv.w * rs * wv.w);
    *(ushort4*)(h + (size_t)row * DD + tid * 4) = hv;
}

// ---------------------------------------------------------------------------
// LayerNorm (final): (x-mu)*rsqrt(var+1e-5)*w + b  (fp32 in, bf16 out)
__global__ __launch_bounds__(256) void lnorm_k(const float* __restrict__ x,
                                               const float* __restrict__ w,
                                               const float* __restrict__ b,
                                               ushort* __restrict__ h) {
    int row = blockIdx.x, tid = threadIdx.x;
    int wave = tid >> 6, lane = tid & 63;
    const float* xr = x + (size_t)row * DD;
    float4 xv = *(const float4*)(xr + tid * 4);
    float s1 = xv.x + xv.y + xv.z + xv.w;
    for (int off = 32; off; off >>= 1) s1 += __shfl_xor(s1, off, 64);
    __shared__ float r1[4], r2[4];
    if (lane == 0) r1[wave] = s1;
    __syncthreads();
    float mu = (r1[0] + r1[1] + r1[2] + r1[3]) * (1.0f / DD);
    float dx0 = xv.x - mu, dx1 = xv.y - mu, dx2 = xv.z - mu, dx3 = xv.w - mu;
    float s2 = dx0 * dx0 + dx1 * dx1 + dx2 * dx2 + dx3 * dx3;
    for (int off = 32; off; off >>= 1) s2 += __shfl_xor(s2, off, 64);
    if (lane == 0) r2[wave] = s2;
    __syncthreads();
    float var = (r2[0] + r2[1] + r2[2] + r2[3]) * (1.0f / DD);
    float rs = rsqrtf(var + 1e-5f);
    float4 wv = *(const float4*)(w + tid * 4);
    float4 bv = *(const float4*)(b + tid * 4);
    ushort4 hv;
    hv.x = f2bf(dx0 * rs * wv.x + bv.x);
    hv.y = f2bf(dx1 * rs * wv.y + bv.y);
    hv.z = f2bf(dx2 * rs * wv.z + bv.z);
    hv.w = f2bf(dx3 * rs * wv.w + bv.w);
    *(ushort4*)(h + (size_t)row * DD + tid * 4) = hv;
}

// ---------------------------------------------------------------------------
// silu(a)*g elementwise, in-place into a (bf16 buffers). 4 elems/thread.
__global__ void silu_k(ushort* __restrict__ a, const ushort* __restrict__ g) {
    int i = (blockIdx.x * 256 + threadIdx.x) * 4;
    ushort4 av = *(const ushort4*)(a + i);
    ushort4 gv = *(const ushort4*)(g + i);
    ushort4 ov;
    {
        float x = bf2f(av.x); ov.x = f2bf(x / (1.0f + __expf(-x)) * bf2f(gv.x));
        float y = bf2f(av.y); ov.y = f2bf(y / (1.0f + __expf(-y)) * bf2f(gv.y));
        float z = bf2f(av.z); ov.z = f2bf(z / (1.0f + __expf(-z)) * bf2f(gv.z));
        float u = bf2f(av.w); ov.w = f2bf(u / (1.0f + __expf(-u)) * bf2f(gv.w));
    }
    *(ushort4*)(a + i) = ov;
}

// ---------------------------------------------------------------------------
// Batched transpose + fp32->bf16 cast: out[N][K] (bf16) <- in[K][N] (fp32).
// 64x64 tiles. grid: (N/64, K/64, batch), 256 threads.
// Vectorized: float4 reads, ushort4 writes (G13).
__global__ __launch_bounds__(256) void transp_k(const float* __restrict__ in,
                                                ushort* __restrict__ out,
                                                int K, int N,
                                                long long inB, long long outB) {
    __shared__ int tbuf[64][65];
    const float* ip = in + (size_t)blockIdx.z * inB;
    ushort* op = out + (size_t)blockIdx.z * outB;
    int n0 = blockIdx.x * 64, k0 = blockIdx.y * 64;
    int tid = threadIdx.x;
#pragma unroll
    for (int jj = 0; jj < 4; ++jj) {
        int idxq = tid + jj * 256;           // 0..1023
        int rr = idxq >> 4;                  // 64 rows (k)
        int cc = (idxq & 15) * 4;            // 16 col-groups of 4 (n)
        float4 f = *(const float4*)(ip + (size_t)(k0 + rr) * N + n0 + cc);
        tbuf[rr][cc]     = f2bf(f.x);
        tbuf[rr][cc + 1] = f2bf(f.y);
        tbuf[rr][cc + 2] = f2bf(f.z);
        tbuf[rr][cc + 3] = f2bf(f.w);
    }
    __syncthreads();
#pragma unroll
    for (int jj = 0; jj < 4; ++jj) {
        int idxq = tid + jj * 256;
        int rr = idxq >> 4;                  // 64 rows (n)
        int cc = (idxq & 15) * 4;            // 16 col-groups of 4 (k)
        ushort4 v;
        v.x = (ushort)tbuf[cc][rr];
        v.y = (ushort)tbuf[cc + 1][rr];
        v.z = (ushort)tbuf[cc + 2][rr];
        v.w = (ushort)tbuf[cc + 3][rr];
        *(ushort4*)(op + (size_t)(n0 + rr) * K + k0 + cc) = v;
    }
}

// ---------------------------------------------------------------------------
// MFMA GEMM: C[M,N] = A[M,K] (bf16 row-major) x B (given as Bt[N,K] bf16
// row-major), fp32 accumulate. 128x128 block tile, BK=32, 256 threads = 4
// waves, each wave a 64x64 subtile (4x4 MFMA 16x16x32 tiles).
// m97 structure: double-buffered linear LDS, global_load_lds width=16 staging,
// ONE barrier per K-step (learn_hip ladder step 3: 517->874 TF).
// Fragment layouts (verified, learn_hip m89/m91/m92):
//   A: lane holds A[m=lane&15][k=quad*8+j]   B: lane holds B[k=quad*8+j][n=lane&15]
//   C/D: col=lane&15, row=quad*4+reg
// Epilogue: optional fp32 bias[col], fp32 residual[row*N+col]; out fp32 or bf16.
template <bool BIAS, bool RESID, bool OUTBF>
__global__ __launch_bounds__(256) void gemm_k(const ushort* __restrict__ A,
                                              const ushort* __restrict__ Bt,
                                              const float* __restrict__ bias,
                                              const float* __restrict__ resid,
                                              void* __restrict__ Cout,
                                              int M, int N, int K) {
    // linear layout required by global_load_lds (wave-uniform base + lane*16)
    __shared__ __align__(16) ushort As[2][128 * 32];
    __shared__ __align__(16) ushort Bs[2][128 * 32];
    const int tid = threadIdx.x;
    const int m0 = blockIdx.y * 128, n0 = blockIdx.x * 128;
    const int wave = tid >> 6, lane = tid & 63;
    const int waveM = (wave >> 1) * 64, waveN = (wave & 1) * 64;
    const int lrow = lane & 15, quad = lane >> 4;

    // staging geometry: wave w stages rows [w*32, w*32+32); two 16-row issues.
    // lane l covers row base + (l>>2), 16B chunk (l&3)*8 elems. LDS row stride
    // 32 elems = 64B, so 64 lanes * 16B = 16 rows per issue, linear. (m97)
    const int srow = wave * 32 + (lane >> 2);
    const int scol = (lane & 3) * 8;
    const ushort* pa = A + (size_t)(m0 + srow) * K + scol;
    const ushort* pb = Bt + (size_t)(n0 + srow) * K + scol;
    ushort* lA = &As[0][0] + wave * 32 * 32;   // wave-uniform
    ushort* lB = &Bs[0][0] + wave * 32 * 32;

    f32x4 acc[4][4];
    f32x4 zero = {0.f, 0.f, 0.f, 0.f};
#pragma unroll
    for (int i = 0; i < 4; i++)
#pragma unroll
        for (int j = 0; j < 4; j++) acc[i][j] = zero;

    const int nk = K >> 5;

#define STAGE(buf, kt)                                                         \
    do {                                                                       \
        const ushort* ga = pa + (size_t)(kt) * 32;                             \
        const ushort* gb = pb + (size_t)(kt) * 32;                             \
        ushort* la = lA + (size_t)(buf) * 128 * 32;                            \
        ushort* lb = lB + (size_t)(buf) * 128 * 32;                            \
        gl_lds16(ga, la);                                                      \
        gl_lds16(ga + (size_t)16 * K, la + 16 * 32);                           \
        gl_lds16(gb, lb);                                                      \
        gl_lds16(gb + (size_t)16 * K, lb + 16 * 32);                           \
    } while (0)

    STAGE(0, 0);
    int cur = 0;
    for (int kt = 0; kt < nk; ++kt) {
        __syncthreads();                 // drains vmcnt -> buf[cur] ready; also
                                         // guards buf[cur^1] reuse from kt-1
        if (kt + 1 < nk) STAGE(cur ^ 1, kt + 1);
        bf16x8 af[4], bfr[4];
#pragma unroll
        for (int i = 0; i < 4; i++)
            af[i] = *(const bf16x8*)&As[cur][(waveM + i * 16 + lrow) * 32 + quad * 8];
#pragma unroll
        for (int j = 0; j < 4; j++)
            bfr[j] = *(const bf16x8*)&Bs[cur][(waveN + j * 16 + lrow) * 32 + quad * 8];
#pragma unroll
        for (int i = 0; i < 4; i++)
#pragma unroll
            for (int j = 0; j < 4; j++)
                acc[i][j] = __builtin_amdgcn_mfma_f32_16x16x32_bf16(af[i], bfr[j], acc[i][j], 0, 0, 0);
        cur ^= 1;
    }
#undef STAGE

    // epilogue
#pragma unroll
    for (int i = 0; i < 4; i++) {
#pragma unroll
        for (int j = 0; j < 4; j++) {
            int colg = n0 + waveN + j * 16 + lrow;
            float bv = BIAS ? bias[colg] : 0.f;
#pragma unroll
            for (int rr = 0; rr < 4; ++rr) {
                int rowg = m0 + waveM + i * 16 + quad * 4 + rr;
                size_t off = (size_t)rowg * N + colg;
                float vv = acc[i][j][rr] + bv;
                if (RESID) vv += resid[off];
                if (OUTBF) ((ushort*)Cout)[off] = f2bf(vv);
                else       ((float*)Cout)[off] = vv;
            }
        }
    }
}

// ---------------------------------------------------------------------------
// Fused causal attention (online softmax). qkv: [B*T, 3072] bf16 where cols
// 0..1023 = q (h*64+hd), 1024.. = k, 2048.. = v. RoPE is identity (see top).
// Block: 256 thr = 4 waves = 4 consecutive query rows of one (b,h).
// Lane j owns output dim j. o: [B*T, 1024] bf16, col h*64+j.
__global__ __launch_bounds__(256) void attn_k(const ushort* __restrict__ qkv,
                                              ushort* __restrict__ o) {
    __shared__ float kt_[64][65];
    __shared__ float vt_[64][65];
    __shared__ float q_l[4][64];
    __shared__ float p_l[4][64];
    int bid = blockIdx.x;
    int bh = bid >> 8;             // 256 blocks per (b,h)
    int t0 = (bid & 255) * 4;
    int b = bh >> 4, h = bh & 15;
    int tid = threadIdx.x, wave = tid >> 6, lane = tid & 63;
    int t = t0 + wave;
    const int LD3 = 3 * DD;
    const size_t base3 = (size_t)(b * TT) * LD3 + h * HDD;
    q_l[wave][lane] = bf2f(qkv[base3 + (size_t)t * LD3 + lane]);
    float mC = -1e30f, lC = 0.f, oacc = 0.f;
    int smax = t0 + 3;
    for (int s0 = 0; s0 <= smax; s0 += 64) {
        __syncthreads();
#pragma unroll
        for (int jj = 0; jj < 16; ++jj) {
            int idxq = tid + jj * 256;
            int i = idxq >> 6, cc = idxq & 63;
            size_t rowb = base3 + (size_t)(s0 + i) * LD3;
            kt_[i][cc] = bf2f(qkv[rowb + DD + cc]);
            vt_[i][cc] = bf2f(qkv[rowb + 2 * DD + cc]);
        }
        __syncthreads();
        int s = s0 + lane;
        bool valid = (s <= t);
        float sc = 0.f;
#pragma unroll
        for (int d = 0; d < 64; ++d) sc += q_l[wave][d] * kt_[lane][d];
        sc = valid ? sc * 0.125f : -1e30f;
        float tm = sc;
        for (int off = 32; off; off >>= 1) tm = fmaxf(tm, __shfl_xor(tm, off, 64));
        float mnew = fmaxf(mC, tm);
        float p = valid ? __expf(sc - mnew) : 0.f;
        float alpha = __expf(mC - mnew);
        float ps = p;
        for (int off = 32; off; off >>= 1) ps += __shfl_xor(ps, off, 64);
        lC = lC * alpha + ps;
        mC = mnew;
        oacc *= alpha;
        p_l[wave][lane] = p;
        __syncthreads();
#pragma unroll
        for (int s2 = 0; s2 < 64; ++s2) oacc += p_l[wave][s2] * vt_[s2][lane];
    }
    o[(size_t)(b * TT + t) * DD + h * HDD + lane] = f2bf(oacc / lC);
}

// ---------------------------------------------------------------------------
extern "C" void kernel_launch(void* const* d_in, const int* in_sizes, int n_in,
                              void* d_out, int out_size, void* d_ws, size_t ws_size,
                              hipStream_t stream) {
    const int*   idx    = (const int*)d_in[0];
    const float* emb    = (const float*)d_in[1];
    const float* wq     = (const float*)d_in[2];
    const float* wk     = (const float*)d_in[3];
    const float* wvv    = (const float*)d_in[4];
    const float* attn_w = (const float*)d_in[5];
    const float* attn_b = (const float*)d_in[6];
    const float* n1_w   = (const float*)d_in[7];
    const float* n2_w   = (const float*)d_in[8];
    const float* f1_w   = (const float*)d_in[9];
    const float* f1_b   = (const float*)d_in[10];
    const float* fs_w   = (const float*)d_in[11];
    const float* fs_b   = (const float*)d_in[12];
    const float* f2_w   = (const float*)d_in[13];
    const float* f2_b   = (const float*)d_in[14];
    const float* ln_w   = (const float*)d_in[15];
    const float* ln_b   = (const float*)d_in[16];
    const float* out_w  = (const float*)d_in[17];
    const float* out_b  = (const float*)d_in[18];

    const int BT = BB * TT;  // 2048

    // Workspace carve-up (~128.5 MB)
    char* ws = (char*)d_ws;
    size_t off = 0;
    float* x = (float*)(ws + off);          off += (size_t)BT * DD * 4;        // 8.39 MB fp32 residual stream
    ushort* wpack = (ushort*)(ws + off);    off += (size_t)VV * DD * 2;        // 65.5 MB packed-weight region (reused)
    ushort* h = (ushort*)(ws + off);        off += (size_t)BT * DD * 2;        // 4.2 MB
    ushort* qkv = (ushort*)(ws + off);      off += (size_t)BT * 3 * DD * 2;    // 12.6 MB
    ushort* ob = (ushort*)(ws + off);       off += (size_t)BT * DD * 2;        // 4.2 MB
    ushort* a = (ushort*)(ws + off);        off += (size_t)BT * FFD * 2;       // 16.8 MB
    ushort* g = (ushort*)(ws + off);        off += (size_t)BT * FFD * 2;       // 16.8 MB

    // sub-pointers inside wpack (per-layer; out_w pack reuses whole region at the end)
    ushort* qkvT = wpack;                        // 3 x 1024x1024
    ushort* attnT = wpack + (size_t)3 * DD * DD; // 1024x1024
    ushort* f1T  = attnT + (size_t)DD * DD;      // 4096x1024
    ushort* fsT  = f1T + (size_t)FFD * DD;       // 4096x4096
    ushort* f2T  = fsT + (size_t)FFD * FFD;      // 1024x4096 (stored [N=1024][K=4096])

    dim3 blk(256);

    embed_k<<<BT, blk, 0, stream>>>(idx, emb, x);

    for (int l = 0; l < LLAY; ++l) {
        const size_t woff_qkv = (size_t)l * HH * DD * HDD;  // 1M elems
        // pack weights into [N][K] bf16
        transp_k<<<dim3(1, 16, 16), blk, 0, stream>>>(wq + woff_qkv, qkvT, DD, HDD,
                                                      (long long)DD * HDD, (long long)HDD * DD);
        transp_k<<<dim3(1, 16, 16), blk, 0, stream>>>(wk + woff_qkv, qkvT + (size_t)DD * DD, DD, HDD,
                                                      (long long)DD * HDD, (long long)HDD * DD);
        transp_k<<<dim3(1, 16, 16), blk, 0, stream>>>(wvv + woff_qkv, qkvT + (size_t)2 * DD * DD, DD, HDD,
                                                      (long long)DD * HDD, (long long)HDD * DD);
        transp_k<<<dim3(16, 16, 1), blk, 0, stream>>>(attn_w + (size_t)l * DD * DD, attnT, DD, DD, 0, 0);
        transp_k<<<dim3(64, 16, 1), blk, 0, stream>>>(f1_w + (size_t)l * DD * FFD, f1T, DD, FFD, 0, 0);
        transp_k<<<dim3(64, 64, 1), blk, 0, stream>>>(fs_w + (size_t)l * FFD * FFD, fsT, FFD, FFD, 0, 0);
        transp_k<<<dim3(16, 64, 1), blk, 0, stream>>>(f2_w + (size_t)l * FFD * DD, f2T, FFD, DD, 0, 0);

        // h = rmsnorm(x, n1_w)
        rmsnorm_k<<<BT, blk, 0, stream>>>(x, n1_w + l * DD, h);
        // qkv = h @ [Wq|Wk|Wv]   (N=3072)
        gemm_k<false, false, true><<<dim3(24, 16), blk, 0, stream>>>(h, qkvT, nullptr, nullptr, qkv,
                                                                     BT, 3 * DD, DD);
        // attention (rope==identity)
        attn_k<<<BB * HH * (TT / 4), blk, 0, stream>>>(qkv, ob);
        // x += o @ attn_w + attn_b
        gemm_k<true, true, false><<<dim3(8, 16), blk, 0, stream>>>(ob, attnT, attn_b + l * DD, x, x,
                                                                   BT, DD, DD);
        // h = rmsnorm(x, n2_w)
        rmsnorm_k<<<BT, blk, 0, stream>>>(x, n2_w + l * DD, h);
        // a = h @ f1_w + f1_b
        gemm_k<true, false, true><<<dim3(32, 16), blk, 0, stream>>>(h, f1T, f1_b + l * FFD, nullptr, a,
                                                                    BT, FFD, DD);
        // g = a @ fs_w + fs_b
        gemm_k<true, false, true><<<dim3(32, 16), blk, 0, stream>>>(a, fsT, fs_b + l * FFD, nullptr, g,
                                                                    BT, FFD, FFD);
        // a = silu(a) * g
        silu_k<<<(BT * FFD) / 1024, blk, 0, stream>>>(a, g);
        // x += a @ f2_w + f2_b
        gemm_k<true, true, false><<<dim3(8, 16), blk, 0, stream>>>(a, f2T, f2_b + l * DD, x, x,
                                                                   BT, DD, FFD);
    }

    // h = layernorm(x)
    lnorm_k<<<BT, blk, 0, stream>>>(x, ln_w, ln_b, h);
    // pack out_w [1024,32000] -> [32000,1024] into wpack (layer weights done)
    transp_k<<<dim3(500, 16, 1), blk, 0, stream>>>(out_w, wpack, DD, VV, 0, 0);
    // logits = h @ out_w + out_b  -> fp32 d_out
    gemm_k<true, false, false><<<dim3(250, 16), blk, 0, stream>>>(h, wpack, out_b, nullptr,
                                                                  (float*)d_out, BT, VV, DD);
}

// Round 2
// 1408.474 us; speedup vs baseline: 1.7913x; 1.7913x over previous
//
#include <hip/hip_runtime.h>

// Problem constants (LLaMA_5669356831047)
#define BB   2
#define TT   1024
#define HH   16
#define DD   1024
#define HDD  64
#define FFD  4096
#define VV   32000
#define LLAY 2
// NOTE: reference rope diag is identically 1.0 (theta = (10000**-2k)//HD == 0) -> RoPE is identity.
// Dtype contract: ALL float tensors fp32; output fp32. bf16 internally for MFMA.

typedef __bf16 bf16x8 __attribute__((ext_vector_type(8)));
typedef float  f32x4  __attribute__((ext_vector_type(4)));
typedef unsigned short u16x8 __attribute__((ext_vector_type(8)));

__device__ __forceinline__ float bf2f(ushort u) {
    return __uint_as_float(((unsigned int)u) << 16);
}
__device__ __forceinline__ ushort f2bf(float f) {
    unsigned int u = __float_as_uint(f);
    u += 0x7fffu + ((u >> 16) & 1u);   // round-to-nearest-even
    return (ushort)(u >> 16);
}

// async global->LDS, 16B per lane. LDS dest must be wave-uniform base; HW
// writes base + lane*16 (learn_hip m97/m104).
__device__ __forceinline__ void gl_lds16(const ushort* g, ushort* l) {
    typedef const __attribute__((address_space(1))) unsigned int* gp_t;
    typedef __attribute__((address_space(3))) unsigned int* lp_t;
    __builtin_amdgcn_global_load_lds((gp_t)g, (lp_t)l, 16, 0, 0);
}

// ---------------------------------------------------------------------------
// Embedding gather: x[row][:] = emb[idx[row]][:]   (fp32 -> fp32)
__global__ void embed_k(const int* __restrict__ idx, const float* __restrict__ emb,
                        float* __restrict__ x) {
    int row = blockIdx.x, tid = threadIdx.x;
    int e = idx[row];
    float4 f = *(const float4*)(emb + (size_t)e * DD + tid * 4);
    *(float4*)(x + (size_t)row * DD + tid * 4) = f;
}

// ---------------------------------------------------------------------------
// RMSNorm: h = x * rsqrt(mean(x^2)+eps) * w   (fp32 in, bf16 out). 1 block/row.
__global__ __launch_bounds__(256) void rmsnorm_k(const float* __restrict__ x,
                                                 const float* __restrict__ w,
                                                 ushort* __restrict__ h) {
    int row = blockIdx.x, tid = threadIdx.x;
    int wave = tid >> 6, lane = tid & 63;
    const float* xr = x + (size_t)row * DD;
    float4 xv = *(const float4*)(xr + tid * 4);
    float s = xv.x * xv.x + xv.y * xv.y + xv.z * xv.z + xv.w * xv.w;
    for (int off = 32; off; off >>= 1) s += __shfl_xor(s, off, 64);
    __shared__ float red[4];
    if (lane == 0) red[wave] = s;
    __syncthreads();
    float tot = red[0] + red[1] + red[2] + red[3];
    float rs = rsqrtf(tot * (1.0f / DD) + 1.1920929e-07f);
    float4 wv = *(const float4*)(w + tid * 4);
    ushort4 hv;
    hv.x = f2bf(xv.x * rs * wv.x);
    hv.y = f2bf(xv.y * rs * wv.y);
    hv.z = f2bf(xv.z * rs * wv.z);
    hv.w = f2bf(xv.w * rs * wv.w);
    *(ushort4*)(h + (size_t)row * DD + tid * 4) = hv;
}

// ---------------------------------------------------------------------------
// LayerNorm (final): (x-mu)*rsqrt(var+1e-5)*w + b  (fp32 in, bf16 out)
__global__ __launch_bounds__(256) void lnorm_k(const float* __restrict__ x,
                                               const float* __restrict__ w,
                                               const float* __restrict__ b,
                                               ushort* __restrict__ h) {
    int row = blockIdx.x, tid = threadIdx.x;
    int wave = tid >> 6, lane = tid & 63;
    const float* xr = x + (size_t)row * DD;
    float4 xv = *(const float4*)(xr + tid * 4);
    float s1 = xv.x + xv.y + xv.z + xv.w;
    for (int off = 32; off; off >>= 1) s1 += __shfl_xor(s1, off, 64);
    __shared__ float r1[4], r2[4];
    if (lane == 0) r1[wave] = s1;
    __syncthreads();
    float mu = (r1[0] + r1[1] + r1[2] + r1[3]) * (1.0f / DD);
    float dx0 = xv.x - mu, dx1 = xv.y - mu, dx2 = xv.z - mu, dx3 = xv.w - mu;
    float s2 = dx0 * dx0 + dx1 * dx1 + dx2 * dx2 + dx3 * dx3;
    for (int off = 32; off; off >>= 1) s2 += __shfl_xor(s2, off, 64);
    if (lane == 0) r2[wave] = s2;
    __syncthreads();
    float var = (r2[0] + r2[1] + r2[2] + r2[3]) * (1.0f / DD);
    float rs = rsqrtf(var + 1e-5f);
    float4 wv = *(const float4*)(w + tid * 4);
    float4 bv = *(const float4*)(b + tid * 4);
    ushort4 hv;
    hv.x = f2bf(dx0 * rs * wv.x + bv.x);
    hv.y = f2bf(dx1 * rs * wv.y + bv.y);
    hv.z = f2bf(dx2 * rs * wv.z + bv.z);
    hv.w = f2bf(dx3 * rs * wv.w + bv.w);
    *(ushort4*)(h + (size_t)row * DD + tid * 4) = hv;
}

// ---------------------------------------------------------------------------
// silu(a)*g elementwise, in-place into a (bf16 buffers). 4 elems/thread.
__global__ void silu_k(ushort* __restrict__ a, const ushort* __restrict__ g) {
    int i = (blockIdx.x * 256 + threadIdx.x) * 4;
    ushort4 av = *(const ushort4*)(a + i);
    ushort4 gv = *(const ushort4*)(g + i);
    ushort4 ov;
    {
        float x = bf2f(av.x); ov.x = f2bf(x / (1.0f + __expf(-x)) * bf2f(gv.x));
        float y = bf2f(av.y); ov.y = f2bf(y / (1.0f + __expf(-y)) * bf2f(gv.y));
        float z = bf2f(av.z); ov.z = f2bf(z / (1.0f + __expf(-z)) * bf2f(gv.z));
        float u = bf2f(av.w); ov.w = f2bf(u / (1.0f + __expf(-u)) * bf2f(gv.w));
    }
    *(ushort4*)(a + i) = ov;
}

// ---------------------------------------------------------------------------
// Batched transpose + fp32->bf16 cast: out[N][K] (bf16) <- in[K][N] (fp32).
// 64x64 tiles. grid: (N/64, K/64, batch), 256 threads.
// Vectorized: float4 reads, ushort4 writes (G13).
__global__ __launch_bounds__(256) void transp_k(const float* __restrict__ in,
                                                ushort* __restrict__ out,
                                                int K, int N,
                                                long long inB, long long outB) {
    __shared__ int tbuf[64][65];
    const float* ip = in + (size_t)blockIdx.z * inB;
    ushort* op = out + (size_t)blockIdx.z * outB;
    int n0 = blockIdx.x * 64, k0 = blockIdx.y * 64;
    int tid = threadIdx.x;
#pragma unroll
    for (int jj = 0; jj < 4; ++jj) {
        int idxq = tid + jj * 256;           // 0..1023
        int rr = idxq >> 4;                  // 64 rows (k)
        int cc = (idxq & 15) * 4;            // 16 col-groups of 4 (n)
        float4 f = *(const float4*)(ip + (size_t)(k0 + rr) * N + n0 + cc);
        tbuf[rr][cc]     = f2bf(f.x);
        tbuf[rr][cc + 1] = f2bf(f.y);
        tbuf[rr][cc + 2] = f2bf(f.z);
        tbuf[rr][cc + 3] = f2bf(f.w);
    }
    __syncthreads();
#pragma unroll
    for (int jj = 0; jj < 4; ++jj) {
        int idxq = tid + jj * 256;
        int rr = idxq >> 4;                  // 64 rows (n)
        int cc = (idxq & 15) * 4;            // 16 col-groups of 4 (k)
        ushort4 v;
        v.x = (ushort)tbuf[cc][rr];
        v.y = (ushort)tbuf[cc + 1][rr];
        v.z = (ushort)tbuf[cc + 2][rr];
        v.w = (ushort)tbuf[cc + 3][rr];
        *(ushort4*)(op + (size_t)(n0 + rr) * K + k0 + cc) = v;
    }
}

// ---------------------------------------------------------------------------
// MFMA GEMM: C[M,N] = A[M,K] (bf16 row-major) x B (given as Bt[N,K] bf16
// row-major), fp32 accumulate. 128x128 block tile, BK=32, 256 threads = 4
// waves, each wave a 64x64 subtile (4x4 MFMA 16x16x32 tiles).
// m97 structure: double-buffered linear LDS, global_load_lds width=16 staging,
// ONE barrier per K-step (learn_hip ladder step 3: 517->874 TF).
// Fragment layouts (verified, learn_hip m89/m91/m92):
//   A: lane holds A[m=lane&15][k=quad*8+j]   B: lane holds B[k=quad*8+j][n=lane&15]
//   C/D: col=lane&15, row=quad*4+reg
// Epilogue: optional fp32 bias[col], fp32 residual[row*N+col]; out fp32 or bf16.
template <bool BIAS, bool RESID, bool OUTBF>
__global__ __launch_bounds__(256) void gemm_k(const ushort* __restrict__ A,
                                              const ushort* __restrict__ Bt,
                                              const float* __restrict__ bias,
                                              const float* __restrict__ resid,
                                              void* __restrict__ Cout,
                                              int M, int N, int K) {
    // linear layout required by global_load_lds (wave-uniform base + lane*16)
    __shared__ __align__(16) ushort As[2][128 * 32];
    __shared__ __align__(16) ushort Bs[2][128 * 32];
    const int tid = threadIdx.x;
    const int m0 = blockIdx.y * 128, n0 = blockIdx.x * 128;
    const int wave = tid >> 6, lane = tid & 63;
    const int waveM = (wave >> 1) * 64, waveN = (wave & 1) * 64;
    const int lrow = lane & 15, quad = lane >> 4;

    // staging geometry: wave w stages rows [w*32, w*32+32); two 16-row issues.
    const int srow = wave * 32 + (lane >> 2);
    const int scol = (lane & 3) * 8;
    const ushort* pa = A + (size_t)(m0 + srow) * K + scol;
    const ushort* pb = Bt + (size_t)(n0 + srow) * K + scol;
    ushort* lA = &As[0][0] + wave * 32 * 32;   // wave-uniform
    ushort* lB = &Bs[0][0] + wave * 32 * 32;

    f32x4 acc[4][4];
    f32x4 zero = {0.f, 0.f, 0.f, 0.f};
#pragma unroll
    for (int i = 0; i < 4; i++)
#pragma unroll
        for (int j = 0; j < 4; j++) acc[i][j] = zero;

    const int nk = K >> 5;

#define STAGE(buf, kt)                                                         \
    do {                                                                       \
        const ushort* ga = pa + (size_t)(kt) * 32;                             \
        const ushort* gb = pb + (size_t)(kt) * 32;                             \
        ushort* la = lA + (size_t)(buf) * 128 * 32;                            \
        ushort* lb = lB + (size_t)(buf) * 128 * 32;                            \
        gl_lds16(ga, la);                                                      \
        gl_lds16(ga + (size_t)16 * K, la + 16 * 32);                           \
        gl_lds16(gb, lb);                                                      \
        gl_lds16(gb + (size_t)16 * K, lb + 16 * 32);                           \
    } while (0)

    STAGE(0, 0);
    int cur = 0;
    for (int kt = 0; kt < nk; ++kt) {
        __syncthreads();                 // drains vmcnt -> buf[cur] ready; also
                                         // guards buf[cur^1] reuse from kt-1
        if (kt + 1 < nk) STAGE(cur ^ 1, kt + 1);
        bf16x8 af[4], bfr[4];
#pragma unroll
        for (int i = 0; i < 4; i++)
            af[i] = *(const bf16x8*)&As[cur][(waveM + i * 16 + lrow) * 32 + quad * 8];
#pragma unroll
        for (int j = 0; j < 4; j++)
            bfr[j] = *(const bf16x8*)&Bs[cur][(waveN + j * 16 + lrow) * 32 + quad * 8];
#pragma unroll
        for (int i = 0; i < 4; i++)
#pragma unroll
            for (int j = 0; j < 4; j++)
                acc[i][j] = __builtin_amdgcn_mfma_f32_16x16x32_bf16(af[i], bfr[j], acc[i][j], 0, 0, 0);
        cur ^= 1;
    }
#undef STAGE

    // epilogue
#pragma unroll
    for (int i = 0; i < 4; i++) {
#pragma unroll
        for (int j = 0; j < 4; j++) {
            int colg = n0 + waveN + j * 16 + lrow;
            float bv = BIAS ? bias[colg] : 0.f;
#pragma unroll
            for (int rr = 0; rr < 4; ++rr) {
                int rowg = m0 + waveM + i * 16 + quad * 4 + rr;
                size_t off = (size_t)rowg * N + colg;
                float vv = acc[i][j][rr] + bv;
                if (RESID) vv += resid[off];
                if (OUTBF) ((ushort*)Cout)[off] = f2bf(vv);
                else       ((float*)Cout)[off] = vv;
            }
        }
    }
}

// ---------------------------------------------------------------------------
// MFMA flash attention (causal, online softmax). qkv: [B*T, 3072] bf16:
// cols 0..1023 = q (h*64+hd), 1024.. = k, 2048.. = v. RoPE identity.
// Block = 128 threads = 2 waves; each wave owns 16 query rows; block owns a
// 32-row q-tile. KV tiles of 64. Fragment layouts identical to gemm_k
// (verified m89/m91):
//   A-frag:  lane holds A[m=lane&15][k=quad*8+j]  (8 contiguous k)
//   B-frag:  lane holds B[k=quad*8+j][n=lane&15]  (from [n][k] row-major)
//   C/D:     col = lane&15, row = quad*4+reg
// QK^T: A=Q (global), B=K (global, [s][d] == [n][k] row-major).
// PV:   A=P (via LDS, [q][s]), B=V^T (LDS vt[d][s] == [n][k] row-major).
// Per-lane softmax state covers rows q = quad*4+r; row-reduce = shfl_xor
// over the 16-lane group (masks 1,2,4,8).
// Block order: descending q-tile length (longest first) for load balance;
// blocks of one (b,h) are 32 apart -> same XCD (bid%8) -> K/V L2 locality.
__global__ __launch_bounds__(128) void attn_k(const ushort* __restrict__ qkv,
                                              ushort* __restrict__ o) {
    __shared__ __align__(16) ushort vt[64 * 80];       // V^T tile, [d][s], stride 80
    __shared__ __align__(16) ushort pl[2 * 16 * 80];   // per-wave P, [q_loc][s_loc], stride 80
    const int bid = blockIdx.x;
    const int bh = bid & 31;
    const int qt = 31 - (bid >> 5);        // descending length
    const int b = bh >> 4, h = bh & 15;
    const int t0 = qt * 32;
    const int tid = threadIdx.x, wave = tid >> 6, lane = tid & 63;
    const int lrow = lane & 15, quad = lane >> 4;
    const int LD3 = 3 * DD;
    const size_t base3 = (size_t)(b * TT) * LD3 + (size_t)h * HDD;
    const int t0w = t0 + wave * 16;

    // Q fragments (held in registers for the whole kernel)
    const ushort* qrow = qkv + base3 + (size_t)(t0w + lrow) * LD3 + quad * 8;
    bf16x8 af0 = *(const bf16x8*)(qrow);
    bf16x8 af1 = *(const bf16x8*)(qrow + 32);

    f32x4 acc_o[4];
    f32x4 zero = {0.f, 0.f, 0.f, 0.f};
#pragma unroll
    for (int n = 0; n < 4; ++n) acc_o[n] = zero;
    float m_r[4], l_r[4];
#pragma unroll
    for (int r = 0; r < 4; ++r) { m_r[r] = -1e30f; l_r[r] = 0.f; }

    ushort* plw = pl + wave * 16 * 80;

    const int smax = t0 + 31;
    for (int s0 = 0; s0 <= smax; s0 += 64) {
        __syncthreads();   // vt/pl from previous iteration fully consumed
        // K fragments direct from global (L2-resident)
        bf16x8 bk[4][2];
#pragma unroll
        for (int j = 0; j < 4; ++j) {
            const ushort* kr = qkv + base3 + (size_t)(s0 + j * 16 + lrow) * LD3 + DD + quad * 8;
            bk[j][0] = *(const bf16x8*)(kr);
            bk[j][1] = *(const bf16x8*)(kr + 32);
        }
        // stage V transposed into LDS: vt[d][s] <- V[s0+s][d]
#pragma unroll
        for (int cc = 0; cc < 4; ++cc) {
            int qch = tid + cc * 128;               // 0..511
            int s = qch & 63, d0 = (qch >> 6) * 8;
            u16x8 vv = *(const u16x8*)(qkv + base3 + (size_t)(s0 + s) * LD3 + 2 * DD + d0);
#pragma unroll
            for (int i = 0; i < 8; ++i) vt[(d0 + i) * 80 + s] = vv[i];
        }
        // QK^T -> S strip [16 q][64 s]
        f32x4 accs[4];
#pragma unroll
        for (int j = 0; j < 4; ++j) {
            accs[j] = zero;
            accs[j] = __builtin_amdgcn_mfma_f32_16x16x32_bf16(af0, bk[j][0], accs[j], 0, 0, 0);
            accs[j] = __builtin_amdgcn_mfma_f32_16x16x32_bf16(af1, bk[j][1], accs[j], 0, 0, 0);
        }
        // online softmax (per lane: rows q = quad*4+r)
        float pv[4][4];   // [j][r]
#pragma unroll
        for (int r = 0; r < 4; ++r) {
            int qg = t0w + quad * 4 + r;
            float scv[4], tmax = -1e30f;
#pragma unroll
            for (int j = 0; j < 4; ++j) {
                int sg = s0 + j * 16 + lrow;
                float sc = (sg <= qg) ? accs[j][r] * 0.125f : -1e30f;
                scv[j] = sc;
                tmax = fmaxf(tmax, sc);
            }
            tmax = fmaxf(tmax, __shfl_xor(tmax, 1, 64));
            tmax = fmaxf(tmax, __shfl_xor(tmax, 2, 64));
            tmax = fmaxf(tmax, __shfl_xor(tmax, 4, 64));
            tmax = fmaxf(tmax, __shfl_xor(tmax, 8, 64));
            float mn = fmaxf(m_r[r], tmax);
            float ps = 0.f;
#pragma unroll
            for (int j = 0; j < 4; ++j) {
                float p = __expf(scv[j] - mn);
                pv[j][r] = p;
                ps += p;
            }
            ps += __shfl_xor(ps, 1, 64);
            ps += __shfl_xor(ps, 2, 64);
            ps += __shfl_xor(ps, 4, 64);
            ps += __shfl_xor(ps, 8, 64);
            float alpha = __expf(m_r[r] - mn);
            l_r[r] = l_r[r] * alpha + ps;
            m_r[r] = mn;
#pragma unroll
            for (int n = 0; n < 4; ++n) acc_o[n][r] *= alpha;
        }
        // P -> LDS (C-layout -> A-fragment layout conversion)
#pragma unroll
        for (int j = 0; j < 4; ++j)
#pragma unroll
            for (int r = 0; r < 4; ++r)
                plw[(quad * 4 + r) * 80 + j * 16 + lrow] = f2bf(pv[j][r]);
        __syncthreads();   // vt visible to all waves; pl write->read ordered
        // PV: O += P @ V
        bf16x8 pa0 = *(const bf16x8*)&plw[lrow * 80 + quad * 8];
        bf16x8 pa1 = *(const bf16x8*)&plw[lrow * 80 + 32 + quad * 8];
#pragma unroll
        for (int n = 0; n < 4; ++n) {
            bf16x8 bv0 = *(const bf16x8*)&vt[(n * 16 + lrow) * 80 + quad * 8];
            bf16x8 bv1 = *(const bf16x8*)&vt[(n * 16 + lrow) * 80 + 32 + quad * 8];
            acc_o[n] = __builtin_amdgcn_mfma_f32_16x16x32_bf16(pa0, bv0, acc_o[n], 0, 0, 0);
            acc_o[n] = __builtin_amdgcn_mfma_f32_16x16x32_bf16(pa1, bv1, acc_o[n], 0, 0, 0);
        }
    }
    // epilogue: O /= l, write bf16
#pragma unroll
    for (int n = 0; n < 4; ++n)
#pragma unroll
        for (int r = 0; r < 4; ++r) {
            int tg = t0w + quad * 4 + r;
            o[(size_t)(b * TT + tg) * DD + h * HDD + n * 16 + lrow] = f2bf(acc_o[n][r] / l_r[r]);
        }
}

// ---------------------------------------------------------------------------
extern "C" void kernel_launch(void* const* d_in, const int* in_sizes, int n_in,
                              void* d_out, int out_size, void* d_ws, size_t ws_size,
                              hipStream_t stream) {
    const int*   idx    = (const int*)d_in[0];
    const float* emb    = (const float*)d_in[1];
    const float* wq     = (const float*)d_in[2];
    const float* wk     = (const float*)d_in[3];
    const float* wvv    = (const float*)d_in[4];
    const float* attn_w = (const float*)d_in[5];
    const float* attn_b = (const float*)d_in[6];
    const float* n1_w   = (const float*)d_in[7];
    const float* n2_w   = (const float*)d_in[8];
    const float* f1_w   = (const float*)d_in[9];
    const float* f1_b   = (const float*)d_in[10];
    const float* fs_w   = (const float*)d_in[11];
    const float* fs_b   = (const float*)d_in[12];
    const float* f2_w   = (const float*)d_in[13];
    const float* f2_b   = (const float*)d_in[14];
    const float* ln_w   = (const float*)d_in[15];
    const float* ln_b   = (const float*)d_in[16];
    const float* out_w  = (const float*)d_in[17];
    const float* out_b  = (const float*)d_in[18];

    const int BT = BB * TT;  // 2048

    // Workspace carve-up (~128.5 MB)
    char* ws = (char*)d_ws;
    size_t off = 0;
    float* x = (float*)(ws + off);          off += (size_t)BT * DD * 4;        // 8.39 MB fp32 residual stream
    ushort* wpack = (ushort*)(ws + off);    off += (size_t)VV * DD * 2;        // 65.5 MB packed-weight region (reused)
    ushort* h = (ushort*)(ws + off);        off += (size_t)BT * DD * 2;        // 4.2 MB
    ushort* qkv = (ushort*)(ws + off);      off += (size_t)BT * 3 * DD * 2;    // 12.6 MB
    ushort* ob = (ushort*)(ws + off);       off += (size_t)BT * DD * 2;        // 4.2 MB
    ushort* a = (ushort*)(ws + off);        off += (size_t)BT * FFD * 2;       // 16.8 MB
    ushort* g = (ushort*)(ws + off);        off += (size_t)BT * FFD * 2;       // 16.8 MB

    // sub-pointers inside wpack (per-layer; out_w pack reuses whole region at the end)
    ushort* qkvT = wpack;                        // 3 x 1024x1024
    ushort* attnT = wpack + (size_t)3 * DD * DD; // 1024x1024
    ushort* f1T  = attnT + (size_t)DD * DD;      // 4096x1024
    ushort* fsT  = f1T + (size_t)FFD * DD;       // 4096x4096
    ushort* f2T  = fsT + (size_t)FFD * FFD;      // 1024x4096 (stored [N=1024][K=4096])

    dim3 blk(256);

    embed_k<<<BT, blk, 0, stream>>>(idx, emb, x);

    for (int l = 0; l < LLAY; ++l) {
        const size_t woff_qkv = (size_t)l * HH * DD * HDD;  // 1M elems
        // pack weights into [N][K] bf16
        transp_k<<<dim3(1, 16, 16), blk, 0, stream>>>(wq + woff_qkv, qkvT, DD, HDD,
                                                      (long long)DD * HDD, (long long)HDD * DD);
        transp_k<<<dim3(1, 16, 16), blk, 0, stream>>>(wk + woff_qkv, qkvT + (size_t)DD * DD, DD, HDD,
                                                      (long long)DD * HDD, (long long)HDD * DD);
        transp_k<<<dim3(1, 16, 16), blk, 0, stream>>>(wvv + woff_qkv, qkvT + (size_t)2 * DD * DD, DD, HDD,
                                                      (long long)DD * HDD, (long long)HDD * DD);
        transp_k<<<dim3(16, 16, 1), blk, 0, stream>>>(attn_w + (size_t)l * DD * DD, attnT, DD, DD, 0, 0);
        transp_k<<<dim3(64, 16, 1), blk, 0, stream>>>(f1_w + (size_t)l * DD * FFD, f1T, DD, FFD, 0, 0);
        transp_k<<<dim3(64, 64, 1), blk, 0, stream>>>(fs_w + (size_t)l * FFD * FFD, fsT, FFD, FFD, 0, 0);
        transp_k<<<dim3(16, 64, 1), blk, 0, stream>>>(f2_w + (size_t)l * FFD * DD, f2T, FFD, DD, 0, 0);

        // h = rmsnorm(x, n1_w)
        rmsnorm_k<<<BT, blk, 0, stream>>>(x, n1_w + l * DD, h);
        // qkv = h @ [Wq|Wk|Wv]   (N=3072)
        gemm_k<false, false, true><<<dim3(24, 16), blk, 0, stream>>>(h, qkvT, nullptr, nullptr, qkv,
                                                                     BT, 3 * DD, DD);
        // attention (rope==identity): 32-row q-tiles, 2 waves/block
        attn_k<<<BB * HH * (TT / 32), dim3(128), 0, stream>>>(qkv, ob);
        // x += o @ attn_w + attn_b
        gemm_k<true, true, false><<<dim3(8, 16), blk, 0, stream>>>(ob, attnT, attn_b + l * DD, x, x,
                                                                   BT, DD, DD);
        // h = rmsnorm(x, n2_w)
        rmsnorm_k<<<BT, blk, 0, stream>>>(x, n2_w + l * DD, h);
        // a = h @ f1_w + f1_b
        gemm_k<true, false, true><<<dim3(32, 16), blk, 0, stream>>>(h, f1T, f1_b + l * FFD, nullptr, a,
                                                                    BT, FFD, DD);
        // g = a @ fs_w + fs_b
        gemm_k<true, false, true><<<dim3(32, 16), blk, 0, stream>>>(a, fsT, fs_b + l * FFD, nullptr, g,
                                                                    BT, FFD, FFD);
        // a = silu(a) * g
        silu_k<<<(BT * FFD) / 1024, blk, 0, stream>>>(a, g);
        // x += a @ f2_w + f2_b
        gemm_k<true, true, false><<<dim3(8, 16), blk, 0, stream>>>(a, f2T, f2_b + l * DD, x, x,
                                                                   BT, DD, FFD);
    }

    // h = layernorm(x)
    lnorm_k<<<BT, blk, 0, stream>>>(x, ln_w, ln_b, h);
    // pack out_w [1024,32000] -> [32000,1024] into wpack (layer weights done)
    transp_k<<<dim3(500, 16, 1), blk, 0, stream>>>(out_w, wpack, DD, VV, 0, 0);
    // logits = h @ out_w + out_b  -> fp32 d_out
    gemm_k<true, false, false><<<dim3(250, 16), blk, 0, stream>>>(h, wpack, out_b, nullptr,
                                                                  (float*)d_out, BT, VV, DD);
}